// Round 7
// baseline (95.434 us; speedup 1.0000x reference)
//
#include <hip/hip_runtime.h>
#include <hip/hip_bf16.h>
#include <stdint.h>
#include <stddef.h>

// Problem constants
#define NIMG 32
#define C_IN 128
#define C_OUT 256
#define HW 56
#define SP 3136            // 56*56
#define STOT (NIMG * SP)   // 100352
#define PD 58              // padded spatial dim
#define KTOT 1152          // 128*9

// GEMM tiling
#define BM 256
#define BN 224             // 448 tiles = 8*56 (XCD-exact)
#define NSLICE 36          // K-slices of 32
#define THREADS 512

typedef __attribute__((ext_vector_type(8))) short bf16x8;
typedef __attribute__((ext_vector_type(4))) float f32x4;

__device__ __forceinline__ void gload16(const void* g, void* l) {
    __builtin_amdgcn_global_load_lds(
        (const __attribute__((address_space(1))) void*)g,
        (__attribute__((address_space(3))) void*)l,
        16, 0, 0);
}

// Memory-clobber only: orders memory ops (ds_read/gload_lds) across the wait,
// leaves register-only MFMAs schedulable.
#define BAR() do { asm volatile("" ::: "memory"); \
                   __builtin_amdgcn_s_barrier();  \
                   asm volatile("" ::: "memory"); } while (0)
#define VMCNT(n) asm volatile("s_waitcnt vmcnt(" #n ")" ::: "memory")

__device__ __forceinline__ unsigned short bf2u(float f) {
    __hip_bfloat16 b = __float2bfloat16(f);
    return *reinterpret_cast<unsigned short*>(&b);
}

// ---------------------------------------------------------------------------
// Prepass (merged):
//  blocks [0, PAD_BLOCKS): pad+transpose x -> padded NHWC bf16 [n][58][58][128]
//  blocks [PAD_BLOCKS, +A_BLOCKS): weights OIHW fp32 -> MFMA-frag-ordered bf16
//    A_arr[slice s][mfrag f][lane l][e 0..7] = W[tap=s>>2][co=f*16+(l&15)]
//                                              [ci=(s&3)*32+(l>>4)*8+e]
//    so an A-frag load in the main loop is ONE coalesced dwordx4 per lane.
// ---------------------------------------------------------------------------
#define PAD_BLOCKS (NIMG * PD)          // 1856
#define A_BLOCKS   (NSLICE * 16 * 64 / 256)  // 144

__global__ __launch_bounds__(256)
void prep_kernel(const float* __restrict__ x, const float* __restrict__ wgt,
                 __hip_bfloat16* __restrict__ xp, __hip_bfloat16* __restrict__ aarr) {
    __shared__ float t[C_IN][HW + 1];
    const int b = blockIdx.x;
    if (b < PAD_BLOCKS) {
        const int hp = b % PD;
        const int n  = b / PD;
        const int h  = hp - 1;
        const bool interior = ((unsigned)h < (unsigned)HW);
        if (interior) {
            for (int idx = threadIdx.x; idx < C_IN * HW; idx += 256) {
                int ci = idx / HW, w = idx - ci * HW;
                t[ci][w] = x[((size_t)n * C_IN + ci) * SP + h * HW + w];
            }
        }
        __syncthreads();
        ushort4* dst = (ushort4*)(xp + ((size_t)n * PD + hp) * PD * C_IN);
        for (int idx = threadIdx.x; idx < PD * C_IN / 4; idx += 256) {
            int el = idx * 4;
            int wp = el >> 7, c0 = el & 127;
            ushort4 v = {0, 0, 0, 0};
            if (interior && wp >= 1 && wp <= HW) {
                int w = wp - 1;
                v.x = bf2u(t[c0 + 0][w]);
                v.y = bf2u(t[c0 + 1][w]);
                v.z = bf2u(t[c0 + 2][w]);
                v.w = bf2u(t[c0 + 3][w]);
            }
            dst[idx] = v;
        }
    } else {
        int idx = (b - PAD_BLOCKS) * 256 + threadIdx.x;  // 0..36863
        int l   = idx & 63;
        int f   = (idx >> 6) & 15;
        int s   = idx >> 10;            // 0..35
        int tap = s >> 2;
        int co  = f * 16 + (l & 15);
        int cib = ((s & 3) << 5) + ((l >> 4) << 3);
        ushort4 v0, v1;
        v0.x = bf2u(wgt[(co * C_IN + cib + 0) * 9 + tap]);
        v0.y = bf2u(wgt[(co * C_IN + cib + 1) * 9 + tap]);
        v0.z = bf2u(wgt[(co * C_IN + cib + 2) * 9 + tap]);
        v0.w = bf2u(wgt[(co * C_IN + cib + 3) * 9 + tap]);
        v1.x = bf2u(wgt[(co * C_IN + cib + 4) * 9 + tap]);
        v1.y = bf2u(wgt[(co * C_IN + cib + 5) * 9 + tap]);
        v1.z = bf2u(wgt[(co * C_IN + cib + 6) * 9 + tap]);
        v1.w = bf2u(wgt[(co * C_IN + cib + 7) * 9 + tap]);
        ushort4* d = (ushort4*)(aarr + (size_t)idx * 8);
        d[0] = v0;
        d[1] = v1;
    }
}

// ---------------------------------------------------------------------------
// Main: implicit GEMM, 256x224 tile, 8 waves (4M x 2N, 64x112 each).
// A: direct global->VGPR, frag-ordered coalesced dwordx4 (L2-hot, 590 KB),
//    loaded one phase ahead; compiler manages its vmcnt (LDA issued BEFORE
//    the counted STG so the reg-wait never drains the staging queue).
// B: LDS ring of 4 regions x 16 KB, staged via gload_lds one region ahead.
// Phase p (p=0..35): VMCNT(6); BAR; RD_B(p+1); LDA(p+1); STG_B(p+3); MM(p).
// VMCNT(6) drains STG(p+1) [issued @ p-2]; newer in flight = LDA(p):4 +
// STG(p+2):2 = 6.  Tail: p=34 -> VMCNT(4); p=35 -> MM only.
// ---------------------------------------------------------------------------
__global__ __launch_bounds__(THREADS, 2)
void conv_mfma_kernel(const __hip_bfloat16* __restrict__ xp,
                      const short* __restrict__ Aarr,
                      const float* __restrict__ bias,
                      float* __restrict__ out) {
    extern __shared__ short smem[];   // 4 regions * 8192 shorts = 64 KiB

    const int tid  = threadIdx.x;
    const int lane = tid & 63;
    const int wid  = tid >> 6;
    const int rl   = lane & 15;
    const int kq   = lane >> 4;
    const int wg   = (blockIdx.x & 7) * 56 + (blockIdx.x >> 3);  // XCD-bijective
    const int s0   = wg * BN;

    // ---- B staging constants (inverse-swizzled global source, rule #21) ----
    const int cg_el = (((lane & 3) ^ ((lane >> 3) & 3)) << 3);
    const int srow  = wid * 16 + (lane >> 2);        // 0..127
    const int ldsw  = wid * 512;                     // wave-uniform LDS dest
    int s_r = s0 + srow;
    int n_  = s_r / SP, rem = s_r - n_ * SP;
    int h_  = rem / HW, w_ = rem - h_ * HW;
    const int bS0 = ((n_ * PD + h_) * PD + w_) * C_IN + cg_el;
    int srow2 = 128 + srow; if (srow2 > BN - 1) srow2 = BN - 1;   // dummy
    s_r = s0 + srow2;
    n_ = s_r / SP; rem = s_r - n_ * SP; h_ = rem / HW; w_ = rem - h_ * HW;
    const int bS1 = ((n_ * PD + h_) * PD + w_) * C_IN + cg_el;

    // ---- compute-phase offsets ----
    const int rch = ((kq ^ ((lane >> 1) & 3)) << 3);   // B read swizzle
    const int wm  = (wid >> 1) * 64;    // 4 M-waves
    const int wn  = (wid & 1) * 112;    // 2 N-waves
    const int bRd = (wn + rl) * 32 + rch;
    const int fbase = (wid >> 1) * 4;   // first M-frag index of this wave

    auto STG = [&](int s) {            // stage B slice s into region s&3
        int tap = s >> 2, ci0 = (s & 3) << 5;
        int kh = (tap * 11) >> 5, kw = tap - kh * 3;
        const __hip_bfloat16* xsrc = xp + (kh * PD + kw) * C_IN + ci0;
        short* Bd = smem + (s & 3) * 8192 + ldsw;
        gload16(xsrc + bS0, Bd);
        gload16(xsrc + bS1, Bd + 4096);
    };
    auto LDA = [&](bf16x8* ga, int s) { // A-frags: coalesced dwordx4 from L2
        const short* base = Aarr + ((size_t)((s * 16 + fbase) * 64 + lane)) * 8;
        #pragma unroll
        for (int mi = 0; mi < 4; ++mi)
            ga[mi] = *(const bf16x8*)(base + mi * 512);
    };
    auto RD = [&](bf16x8* fb, int r) {  // B-frags from LDS
        const short* Bb = smem + r * 8192;
        #pragma unroll
        for (int j = 0; j < 7; ++j)
            fb[j] = *(const bf16x8*)(Bb + bRd + j * 512);
    };

    // bias preload (tile-invariant)
    float bv[4][4];
    #pragma unroll
    for (int mi = 0; mi < 4; ++mi)
        #pragma unroll
        for (int j = 0; j < 4; ++j)
            bv[mi][j] = bias[wm + mi * 16 + (kq << 2) + j];

    f32x4 acc[4][7] = {};
    bf16x8 ga0[4], ga1[4], fb0[7], fb1[7];

    #define MM(GA, FB) do { \
        __builtin_amdgcn_s_setprio(1); \
        _Pragma("unroll") \
        for (int mi = 0; mi < 4; ++mi) \
            _Pragma("unroll") \
            for (int ni = 0; ni < 7; ++ni) \
                acc[mi][ni] = __builtin_amdgcn_mfma_f32_16x16x32_bf16( \
                    GA[mi], FB[ni], acc[mi][ni], 0, 0, 0); \
        __builtin_amdgcn_s_setprio(0); \
    } while (0)

    // ---- prologue: B slices 0,1,2 staged; A slice 0 in regs ----
    STG(0); STG(1); STG(2);   // 6 vm
    LDA(ga0, 0);              // 4 vm
    VMCNT(8);                 // drain STG(0): newer = STG(1,2):4 + LDA(0):4
    BAR();
    RD(fb0, 0);

    for (int t = 0; t < 18; ++t) {
        const int p0 = 2 * t;
        // ---- even phase p0: MM slice p0 (ga0, fb0) ----
        if (t == 17) { VMCNT(4); } else { VMCNT(6); }
        BAR();
        RD(fb1, (p0 + 1) & 3);
        LDA(ga1, p0 + 1);
        if (p0 <= 32) STG(p0 + 3);
        MM(ga0, fb0);

        // ---- odd phase p1 = p0+1: MM slice p1 (ga1, fb1) ----
        if (t < 17) {
            VMCNT(6);
            BAR();
            RD(fb0, (p0 + 2) & 3);
            LDA(ga0, p0 + 2);
            if (p0 + 1 <= 32) STG(p0 + 4);
            MM(ga1, fb1);
        } else {
            MM(ga1, fb1);     // p=35: frags guarded by compiler waits
        }
    }
    #undef MM

    // ---- epilogue: D col = spatial (lane&15), row = co ----
    #pragma unroll
    for (int ni = 0; ni < 7; ++ni) {
        int s  = s0 + wn + ni * 16 + rl;
        int n  = s / SP;
        int si = s - n * SP;
        float* obase = out + (size_t)n * C_OUT * SP + si;
        #pragma unroll
        for (int mi = 0; mi < 4; ++mi) {
            int cob = wm + mi * 16 + (kq << 2);
            #pragma unroll
            for (int j = 0; j < 4; ++j) {
                obase[(size_t)(cob + j) * SP] = acc[mi][ni][j] + bv[mi][j];
            }
        }
    }
}

// ---------------------------------------------------------------------------
// Fallback: direct fp32 conv (only if ws too small). Slow but correct.
// ---------------------------------------------------------------------------
__global__ void conv_direct_kernel(const float* __restrict__ x,
                                   const float* __restrict__ wgt,
                                   const float* __restrict__ bias,
                                   float* __restrict__ out) {
    long idx = (long)blockIdx.x * 256 + threadIdx.x;
    if (idx >= (long)NIMG * C_OUT * SP) return;
    int si = (int)(idx % SP);
    int co = (int)((idx / SP) % C_OUT);
    int n  = (int)(idx / ((long)SP * C_OUT));
    int h = si / HW, w = si - (si / HW) * HW;
    float acc = bias[co];
    for (int ci = 0; ci < C_IN; ++ci) {
        const float* xr = x + ((size_t)n * C_IN + ci) * SP;
        const float* wr = wgt + ((size_t)co * C_IN + ci) * 9;
        #pragma unroll
        for (int kh = 0; kh < 3; ++kh) {
            int ih = h + kh - 1;
            if (ih < 0 || ih >= HW) continue;
            #pragma unroll
            for (int kw = 0; kw < 3; ++kw) {
                int iw = w + kw - 1;
                if (iw < 0 || iw >= HW) continue;
                acc += xr[ih * HW + iw] * wr[kh * 3 + kw];
            }
        }
    }
    out[idx] = acc;
}

// ---------------------------------------------------------------------------
extern "C" void kernel_launch(void* const* d_in, const int* in_sizes, int n_in,
                              void* d_out, int out_size, void* d_ws, size_t ws_size,
                              hipStream_t stream) {
    const float* x    = (const float*)d_in[0];
    const float* wgt  = (const float*)d_in[1];
    const float* bias = (const float*)d_in[2];
    float* out = (float*)d_out;

    const size_t xp_bytes = (size_t)NIMG * PD * PD * C_IN * sizeof(__hip_bfloat16);
    const size_t aa_bytes = (size_t)NSLICE * 16 * 64 * 8 * sizeof(__hip_bfloat16);

    if (ws_size >= xp_bytes + aa_bytes) {
        __hip_bfloat16* xp = (__hip_bfloat16*)d_ws;
        __hip_bfloat16* aa = (__hip_bfloat16*)((char*)d_ws + xp_bytes);

        prep_kernel<<<PAD_BLOCKS + A_BLOCKS, 256, 0, stream>>>(x, wgt, xp, aa);

        hipFuncSetAttribute((const void*)conv_mfma_kernel,
                            hipFuncAttributeMaxDynamicSharedMemorySize, 65536);
        conv_mfma_kernel<<<STOT / BN, THREADS, 65536, stream>>>(
            xp, (const short*)aa, bias, out);
    } else {
        long total = (long)NIMG * C_OUT * SP;
        conv_direct_kernel<<<(int)((total + 255) / 256), 256, 0, stream>>>(
            x, wgt, bias, out);
    }
}